// Round 2
// baseline (79.865 us; speedup 1.0000x reference)
//
#include <hip/hip_runtime.h>

#define L 32768           // 32*32*32
#define NC 96

// Output layout: out[b][s][c][l], s in 0..11
// s = (q>>1)*4 + (q&1) for base scans q=0..5; flip scan = s+2.
// q0: l=(i,j,k)  q1: l=(i,k,j)  q2: l=(j,k,i)  q3: l=(j,i,k)  q4: l=(k,i,j)  q5: l=(k,j,i)
// input addr within slice = i*1024 + j*32 + k

__global__ __launch_bounds__(256) void cross_scan3d(const float* __restrict__ in,
                                                    float* __restrict__ out) {
    __shared__ float lds[8][32][33];   // 33.8 KB -> 4 blocks/CU

    const int blk   = blockIdx.x;     // 0 .. B*C*6-1
    const int chunk = blockIdx.y;     // 0..3
    const int q  = blk % 6;
    const int bc = blk / 6;           // b*96 + c
    const int b  = bc / NC;
    const int c  = bc % NC;
    const int tid = threadIdx.x;

    const int s_base = (q >> 1) * 4 + (q & 1);

    const float4* in4 = (const float4*)(in + (size_t)bc * L);
    float4* o_base = (float4*)(out + ((size_t)(b * 12 + s_base)     * NC + c) * L);
    float4* o_flip = (float4*)(out + ((size_t)(b * 12 + s_base + 2) * NC + c) * L);

    if (q == 0) {
        // identity copy + reverse
        const int t0 = chunk * 2048;
        #pragma unroll
        for (int it = 0; it < 8; ++it) {
            int t = t0 + it * 256 + tid;
            float4 v = in4[t];
            o_base[t] = v;
            float4 r = {v.w, v.z, v.y, v.x};
            o_flip[8191 - t] = r;
        }
    } else if (q == 3) {
        // l = j*1024 + i*32 + k : row remap, k contiguous both sides
        const int t0 = chunk * 2048;
        #pragma unroll
        for (int it = 0; it < 8; ++it) {
            int t = t0 + it * 256 + tid;
            int c4  = t & 7;          // float4 within row
            int row = t >> 3;         // output row = j*32 + i
            int j = row >> 5, i = row & 31;
            float4 v = in4[(((i << 5) | j) << 3) + c4];
            o_base[t] = v;
            float4 r = {v.w, v.z, v.y, v.x};
            o_flip[8191 - t] = r;
        }
    } else {
        // Tiled transpose over (k, cc) planes; 8 planes batched per barrier.
        //   input addr = w*Sw_in + cc*Sc_in + k
        //   output l   = w*Sw_out + k*Sk_out + cc
        const int Sw_in  = (q == 1 || q == 4) ? 1024 : 32;
        const int Sc_in  = 1056 - Sw_in;            // the other of {1024, 32}
        const int Sw_out = (q <= 2) ? 1024 : 32;    // q1,q2 -> 1024 ; q4,q5 -> 32
        const int Sk_out = 1056 - Sw_out;

        const float* src = in + (size_t)bc * L;

        const int cc_ld = tid >> 3, k4 = tid & 7;   // load indices
        const int k_st  = tid >> 3, c4 = tid & 7;   // store indices
        const int w0 = chunk * 8;

        // 8 independent global loads up front (MLP)
        float4 v0 = ((const float4*)(src + (w0 + 0) * Sw_in + cc_ld * Sc_in))[k4];
        float4 v1 = ((const float4*)(src + (w0 + 1) * Sw_in + cc_ld * Sc_in))[k4];
        float4 v2 = ((const float4*)(src + (w0 + 2) * Sw_in + cc_ld * Sc_in))[k4];
        float4 v3 = ((const float4*)(src + (w0 + 3) * Sw_in + cc_ld * Sc_in))[k4];
        float4 v4 = ((const float4*)(src + (w0 + 4) * Sw_in + cc_ld * Sc_in))[k4];
        float4 v5 = ((const float4*)(src + (w0 + 5) * Sw_in + cc_ld * Sc_in))[k4];
        float4 v6 = ((const float4*)(src + (w0 + 6) * Sw_in + cc_ld * Sc_in))[k4];
        float4 v7 = ((const float4*)(src + (w0 + 7) * Sw_in + cc_ld * Sc_in))[k4];

        const int kb = k4 * 4;
        #define STASH(p, V) \
            lds[p][cc_ld][kb + 0] = V.x; lds[p][cc_ld][kb + 1] = V.y; \
            lds[p][cc_ld][kb + 2] = V.z; lds[p][cc_ld][kb + 3] = V.w;
        STASH(0, v0) STASH(1, v1) STASH(2, v2) STASH(3, v3)
        STASH(4, v4) STASH(5, v5) STASH(6, v6) STASH(7, v7)
        #undef STASH

        __syncthreads();

        #pragma unroll
        for (int p = 0; p < 8; ++p) {
            int base4 = ((w0 + p) * Sw_out + k_st * Sk_out) >> 2;
            float4 o;
            o.x = lds[p][c4 * 4 + 0][k_st];
            o.y = lds[p][c4 * 4 + 1][k_st];
            o.z = lds[p][c4 * 4 + 2][k_st];
            o.w = lds[p][c4 * 4 + 3][k_st];
            o_base[base4 + c4] = o;
            float4 r = {o.w, o.z, o.y, o.x};
            o_flip[8191 - base4 - c4] = r;
        }
    }
}

extern "C" void kernel_launch(void* const* d_in, const int* in_sizes, int n_in,
                              void* d_out, int out_size, void* d_ws, size_t ws_size,
                              hipStream_t stream) {
    const float* in = (const float*)d_in[0];
    float* out = (float*)d_out;
    const int bc_count = in_sizes[0] / L;   // B*C = 192
    dim3 grid(bc_count * 6, 4);
    cross_scan3d<<<grid, 256, 0, stream>>>(in, out);
}

// Round 3
// 64.944 us; speedup vs baseline: 1.2297x; 1.2297x over previous
//
#include <hip/hip_runtime.h>

#define L 32768           // 32*32*32
#define NC 96

// Output: out[b][s][c][l], s in 0..11.  q->s: q0->0 q1->1 q2->4 q3->5 q4->8 q5->9, flip = s+2
// q0: l=(i,j,k)  q1: l=(i,k,j)  q2: l=(j,k,i)  q3: l=(j,i,k)  q4: l=(k,i,j)  q5: l=(k,j,i)
// input addr = i*1024 + j*32 + k
//
// Family decomposition (read input once per family):
//   i-block (type 0): planes = i, lds[p][j][k]  -> q0 (identity), q1 (T contig), q4 (T scatter)
//   j-block (type 1): planes = j, lds[p][i][k]  -> q3 (identity), q2 (T contig), q5 (T scatter)

__global__ __launch_bounds__(256) void cross_scan3d(const float* __restrict__ in,
                                                    float* __restrict__ out) {
    __shared__ float lds[8][32][33];   // 33.8 KB -> 4 blocks/CU

    const int bx   = blockIdx.x;       // bc*2 + type
    const int type = bx & 1;
    const int bc   = bx >> 1;
    const int b    = bc / NC;
    const int c    = bc % NC;
    const int w0   = blockIdx.y * 8;   // plane chunk base
    const int tid  = threadIdx.x;

    const int row = tid >> 3;          // 0..31
    const int k4  = tid & 7;           // float4 index within 32-float row

    const float4* src4 = (const float4*)(in + (size_t)bc * L);

    const int sI = type ? 5 : 0;       // identity scan
    const int sT = type ? 4 : 1;       // transpose, contiguous planes
    const int sS = type ? 9 : 8;       // transpose, scattered planes

    float4* oI  = (float4*)(out + ((size_t)(b*12 + sI    )*NC + c) * L);
    float4* oIf = (float4*)(out + ((size_t)(b*12 + sI + 2)*NC + c) * L);
    float4* oT  = (float4*)(out + ((size_t)(b*12 + sT    )*NC + c) * L);
    float4* oTf = (float4*)(out + ((size_t)(b*12 + sT + 2)*NC + c) * L);
    float4* oS  = (float4*)(out + ((size_t)(b*12 + sS    )*NC + c) * L);
    float4* oSf = (float4*)(out + ((size_t)(b*12 + sS + 2)*NC + c) * L);

    // ---- load 8 planes (each element of this chunk read exactly once) ----
    float4 v0, v1, v2, v3, v4, v5, v6, v7;
    #define LADDR(it) (type ? (row*256 + (w0+(it))*8 + k4) : ((w0+(it))*256 + row*8 + k4))
    v0 = src4[LADDR(0)]; v1 = src4[LADDR(1)]; v2 = src4[LADDR(2)]; v3 = src4[LADDR(3)];
    v4 = src4[LADDR(4)]; v5 = src4[LADDR(5)]; v6 = src4[LADDR(6)]; v7 = src4[LADDR(7)];
    #undef LADDR

    #define STASH(p, V) \
        lds[p][row][k4*4+0] = V.x; lds[p][row][k4*4+1] = V.y; \
        lds[p][row][k4*4+2] = V.z; lds[p][row][k4*4+3] = V.w;
    STASH(0, v0) STASH(1, v1) STASH(2, v2) STASH(3, v3)
    STASH(4, v4) STASH(5, v5) STASH(6, v6) STASH(7, v7)
    #undef STASH

    __syncthreads();

    // ---- emit 6 streams per plane ----
    #pragma unroll
    for (int p = 0; p < 8; ++p) {
        const int gp = w0 + p;

        float4 a;                          // identity fragment
        a.x = lds[p][row][k4*4+0];
        a.y = lds[p][row][k4*4+1];
        a.z = lds[p][row][k4*4+2];
        a.w = lds[p][row][k4*4+3];

        float4 t;                          // transposed fragment T[row][k4*4+e]
        t.x = lds[p][k4*4+0][row];
        t.y = lds[p][k4*4+1][row];
        t.z = lds[p][k4*4+2][row];
        t.w = lds[p][k4*4+3][row];

        const int l0 = gp*256 + row*8 + k4;    // identity & T-contig float4 index
        const int lS = row*256 + gp*8 + k4;    // T-scatter float4 index

        float4 ar = {a.w, a.z, a.y, a.x};
        float4 tr = {t.w, t.z, t.y, t.x};

        oI [l0]        = a;
        oIf[8191 - l0] = ar;
        oT [l0]        = t;
        oTf[8191 - l0] = tr;
        oS [lS]        = t;
        oSf[8191 - lS] = tr;
    }
}

extern "C" void kernel_launch(void* const* d_in, const int* in_sizes, int n_in,
                              void* d_out, int out_size, void* d_ws, size_t ws_size,
                              hipStream_t stream) {
    const float* in = (const float*)d_in[0];
    float* out = (float*)d_out;
    const int bc_count = in_sizes[0] / L;   // B*C = 192
    dim3 grid(bc_count * 2, 4);             // (bc, family) x plane-chunk
    cross_scan3d<<<grid, 256, 0, stream>>>(in, out);
}

// Round 4
// 64.148 us; speedup vs baseline: 1.2450x; 1.0124x over previous
//
#include <hip/hip_runtime.h>

#define L 32768           // 32*32*32
#define NC 96
#define PL 4              // planes per block

typedef float f4 __attribute__((ext_vector_type(4)));

// Output: out[b][s][c][l], s in 0..11.  q->s: q0->0 q1->1 q2->4 q3->5 q4->8 q5->9, flip = s+2
// q0: l=(i,j,k)  q1: l=(i,k,j)  q2: l=(j,k,i)  q3: l=(j,i,k)  q4: l=(k,i,j)  q5: l=(k,j,i)
// input addr = i*1024 + j*32 + k
//
// Family decomposition (input read once per family):
//   i-block (type 0): planes = i, lds[p][j][k]  -> q0 (identity), q1 (T contig), q4 (T scatter)
//   j-block (type 1): planes = j, lds[p][i][k]  -> q3 (identity), q2 (T contig), q5 (T scatter)

__global__ __launch_bounds__(256) void cross_scan3d(const float* __restrict__ in,
                                                    float* __restrict__ out) {
    __shared__ float lds[PL][32][33];   // 16.9 KB -> 8 blocks/CU (32 waves)

    const int bx   = blockIdx.x;       // bc*2 + type
    const int type = bx & 1;
    const int bc   = bx >> 1;
    const int b    = bc / NC;
    const int c    = bc % NC;
    const int w0   = blockIdx.y * PL;  // plane chunk base
    const int tid  = threadIdx.x;

    const int row = tid >> 3;          // 0..31
    const int k4  = tid & 7;           // float4 index within 32-float row

    const f4* src4 = (const f4*)(in + (size_t)bc * L);

    const int sI = type ? 5 : 0;       // identity scan
    const int sT = type ? 4 : 1;       // transpose, contiguous planes
    const int sS = type ? 9 : 8;       // transpose, scattered planes

    f4* oI  = (f4*)(out + ((size_t)(b*12 + sI    )*NC + c) * L);
    f4* oIf = (f4*)(out + ((size_t)(b*12 + sI + 2)*NC + c) * L);
    f4* oT  = (f4*)(out + ((size_t)(b*12 + sT    )*NC + c) * L);
    f4* oTf = (f4*)(out + ((size_t)(b*12 + sT + 2)*NC + c) * L);
    f4* oS  = (f4*)(out + ((size_t)(b*12 + sS    )*NC + c) * L);
    f4* oSf = (f4*)(out + ((size_t)(b*12 + sS + 2)*NC + c) * L);

    // ---- load PL planes (each element of this chunk read exactly once) ----
    f4 v0, v1, v2, v3;
    #define LADDR(it) (type ? (row*256 + (w0+(it))*8 + k4) : ((w0+(it))*256 + row*8 + k4))
    v0 = src4[LADDR(0)]; v1 = src4[LADDR(1)]; v2 = src4[LADDR(2)]; v3 = src4[LADDR(3)];
    #undef LADDR

    #define STASH(p, V) \
        lds[p][row][k4*4+0] = V.x; lds[p][row][k4*4+1] = V.y; \
        lds[p][row][k4*4+2] = V.z; lds[p][row][k4*4+3] = V.w;
    STASH(0, v0) STASH(1, v1) STASH(2, v2) STASH(3, v3)
    #undef STASH

    __syncthreads();

    // ---- emit 6 streams per plane (non-temporal: output is write-once) ----
    #pragma unroll
    for (int p = 0; p < PL; ++p) {
        const int gp = w0 + p;

        f4 a;                          // identity fragment
        a.x = lds[p][row][k4*4+0];
        a.y = lds[p][row][k4*4+1];
        a.z = lds[p][row][k4*4+2];
        a.w = lds[p][row][k4*4+3];

        f4 t;                          // transposed fragment T[row][k4*4+e]
        t.x = lds[p][k4*4+0][row];
        t.y = lds[p][k4*4+1][row];
        t.z = lds[p][k4*4+2][row];
        t.w = lds[p][k4*4+3][row];

        const int l0 = gp*256 + row*8 + k4;    // identity & T-contig float4 index
        const int lS = row*256 + gp*8 + k4;    // T-scatter float4 index

        f4 ar = {a.w, a.z, a.y, a.x};
        f4 tr = {t.w, t.z, t.y, t.x};

        __builtin_nontemporal_store(a,  oI  + l0);
        __builtin_nontemporal_store(ar, oIf + (8191 - l0));
        __builtin_nontemporal_store(t,  oT  + l0);
        __builtin_nontemporal_store(tr, oTf + (8191 - l0));
        __builtin_nontemporal_store(t,  oS  + lS);
        __builtin_nontemporal_store(tr, oSf + (8191 - lS));
    }
}

extern "C" void kernel_launch(void* const* d_in, const int* in_sizes, int n_in,
                              void* d_out, int out_size, void* d_ws, size_t ws_size,
                              hipStream_t stream) {
    const float* in = (const float*)d_in[0];
    float* out = (float*)d_out;
    const int bc_count = in_sizes[0] / L;   // B*C = 192
    dim3 grid(bc_count * 2, 32 / PL);       // (bc, family) x plane-chunk
    cross_scan3d<<<grid, 256, 0, stream>>>(in, out);
}

// Round 5
// 63.924 us; speedup vs baseline: 1.2494x; 1.0035x over previous
//
#include <hip/hip_runtime.h>

#define L 32768           // 32*32*32
#define NC 96

typedef float f4 __attribute__((ext_vector_type(4)));

// Output: out[b][s][c][l], s in 0..11.  flip = s+2
// q0->s0: l=i*1024+j*32+k   q1->s1: l=i*1024+k*32+j
// q2->s4: l=j*1024+k*32+i   q3->s5: l=j*1024+i*32+k
// q4->s8: l=k*1024+i*32+j   q5->s9: l=k*1024+j*32+i
// input addr = i*1024 + j*32 + k
//
// Type A: i-slab [s0:s0+8) x 32j x 32k -> q0,q1,q4 (+flips). Contiguous 32KB read.
// Type B: j-slab 32i x [s0:s0+8) x 32k -> q3,q2,q5 (+flips). 1KB-island read.
// All write streams: >=1KB contiguous per wave store burst.

__global__ __launch_bounds__(256) void cross_scan3d(const float* __restrict__ in,
                                                    float* __restrict__ out) {
    __shared__ float lds[8480];   // A: 8*1057=8456 ; B: 32*265=8480 floats (33.9 KB)

    const int bx   = blockIdx.x;       // bc*2 + type
    const int type = bx & 1;
    const int bc   = bx >> 1;
    const int b    = bc / NC;
    const int c    = bc % NC;
    const int s0   = blockIdx.y * 8;   // slab base
    const int tid  = threadIdx.x;

    const f4* src4 = (const f4*)(in + (size_t)bc * L);
    #define OPTR(s) ((f4*)(out + ((size_t)((b)*12 + (s)) * NC + (c)) * L))
    #define NT(p, v) __builtin_nontemporal_store((v), (p))

    if (type == 0) {
        f4* o0  = OPTR(0);  f4* o0f = OPTR(2);
        f4* o1  = OPTR(1);  f4* o1f = OPTR(3);
        f4* o4  = OPTR(8);  f4* o4f = OPTR(10);

        // ---- load slab (contiguous); q0/q0f straight from registers ----
        const int jj = tid >> 3, k4 = tid & 7;   // rem decode: j, k-float4
        #pragma unroll
        for (int it = 0; it < 8; ++it) {
            f4 v = src4[(s0 + it) * 256 + tid];
            float* d = &lds[it * 1057 + jj * 33 + k4 * 4];
            d[0] = v.x; d[1] = v.y; d[2] = v.z; d[3] = v.w;
            int o = (s0 + it) * 256 + tid;
            NT(o0 + o, v);
            f4 vr = { v.w, v.z, v.y, v.x };
            NT(o0f + (8191 - o), vr);
        }
        __syncthreads();

        // ---- pass {q1,q1f}: per plane it, out (k,j) contiguous 4KB ----
        const int k_o = tid >> 3, j4 = tid & 7;
        #pragma unroll
        for (int it = 0; it < 8; ++it) {
            f4 t;
            t.x = lds[it * 1057 + (j4 * 4 + 0) * 33 + k_o];
            t.y = lds[it * 1057 + (j4 * 4 + 1) * 33 + k_o];
            t.z = lds[it * 1057 + (j4 * 4 + 2) * 33 + k_o];
            t.w = lds[it * 1057 + (j4 * 4 + 3) * 33 + k_o];
            int o = (s0 + it) * 256 + tid;
            NT(o1 + o, t);
            f4 tr = { t.w, t.z, t.y, t.x };
            NT(o1f + (8191 - o), tr);
        }

        // ---- pass {q4,q4f}: lane=(i_loc,j4), loop k -> 1KB islands ----
        const int qd = tid >> 6, il = (tid >> 3) & 7, j4b = tid & 7;
        #pragma unroll
        for (int n = 0; n < 8; ++n) {
            int ko = qd * 8 + n;
            f4 t;
            t.x = lds[il * 1057 + (j4b * 4 + 0) * 33 + ko];
            t.y = lds[il * 1057 + (j4b * 4 + 1) * 33 + ko];
            t.z = lds[il * 1057 + (j4b * 4 + 2) * 33 + ko];
            t.w = lds[il * 1057 + (j4b * 4 + 3) * 33 + ko];
            int o = ko * 256 + (s0 + il) * 8 + j4b;
            NT(o4 + o, t);
            f4 tr = { t.w, t.z, t.y, t.x };
            NT(o4f + (8191 - o), tr);
        }
    } else {
        f4* o3  = OPTR(5);  f4* o3f = OPTR(7);
        f4* o2  = OPTR(4);  f4* o2f = OPTR(6);
        f4* o5  = OPTR(9);  f4* o5f = OPTR(11);

        // ---- load j-slab: per it, i = it*4 + (tid>>6), rem=(j_loc,k4) ----
        #pragma unroll
        for (int it = 0; it < 8; ++it) {
            int i   = it * 4 + (tid >> 6);
            int rem = tid & 63;                      // j_loc = rem>>3, k4 = rem&7
            f4 v = src4[i * 256 + s0 * 8 + rem];
            float* d = &lds[i * 265 + (rem >> 3) * 33 + (rem & 7) * 4];
            d[0] = v.x; d[1] = v.y; d[2] = v.z; d[3] = v.w;
        }
        __syncthreads();

        // ---- pass {q3,q3f}: per plane j_loc=it, out (i,k) contiguous 4KB ----
        const int i_o = tid >> 3, k4 = tid & 7;
        #pragma unroll
        for (int it = 0; it < 8; ++it) {
            f4 a;
            a.x = lds[i_o * 265 + it * 33 + k4 * 4 + 0];
            a.y = lds[i_o * 265 + it * 33 + k4 * 4 + 1];
            a.z = lds[i_o * 265 + it * 33 + k4 * 4 + 2];
            a.w = lds[i_o * 265 + it * 33 + k4 * 4 + 3];
            int o = (s0 + it) * 256 + tid;
            NT(o3 + o, a);
            f4 ar = { a.w, a.z, a.y, a.x };
            NT(o3f + (8191 - o), ar);
        }

        // ---- pass {q2,q2f}: per plane it, out (k,i) contiguous 4KB ----
        const int k_o = tid >> 3, i4 = tid & 7;
        #pragma unroll
        for (int it = 0; it < 8; ++it) {
            f4 t;
            t.x = lds[(i4 * 4 + 0) * 265 + it * 33 + k_o];
            t.y = lds[(i4 * 4 + 1) * 265 + it * 33 + k_o];
            t.z = lds[(i4 * 4 + 2) * 265 + it * 33 + k_o];
            t.w = lds[(i4 * 4 + 3) * 265 + it * 33 + k_o];
            int o = (s0 + it) * 256 + tid;
            NT(o2 + o, t);
            f4 tr = { t.w, t.z, t.y, t.x };
            NT(o2f + (8191 - o), tr);
        }

        // ---- pass {q5,q5f}: lane=(j_loc,i4), loop k -> 1KB islands ----
        const int qd = tid >> 6, jl = (tid >> 3) & 7, i4b = tid & 7;
        #pragma unroll
        for (int n = 0; n < 8; ++n) {
            int ko = qd * 8 + n;
            f4 t;
            t.x = lds[(i4b * 4 + 0) * 265 + jl * 33 + ko];
            t.y = lds[(i4b * 4 + 1) * 265 + jl * 33 + ko];
            t.z = lds[(i4b * 4 + 2) * 265 + jl * 33 + ko];
            t.w = lds[(i4b * 4 + 3) * 265 + jl * 33 + ko];
            int o = ko * 256 + (s0 + jl) * 8 + i4b;
            NT(o5 + o, t);
            f4 tr = { t.w, t.z, t.y, t.x };
            NT(o5f + (8191 - o), tr);
        }
    }
    #undef OPTR
    #undef NT
}

extern "C" void kernel_launch(void* const* d_in, const int* in_sizes, int n_in,
                              void* d_out, int out_size, void* d_ws, size_t ws_size,
                              hipStream_t stream) {
    const float* in = (const float*)d_in[0];
    float* out = (float*)d_out;
    const int bc_count = in_sizes[0] / L;   // B*C = 192
    dim3 grid(bc_count * 2, 4);             // (bc, type) x slab
    cross_scan3d<<<grid, 256, 0, stream>>>(in, out);
}

// Round 6
// 61.728 us; speedup vs baseline: 1.2938x; 1.0356x over previous
//
#include <hip/hip_runtime.h>

#define L 32768           // 32*32*32
#define NC 96
#define LDS_FLOATS (32 * 1057)          // A(i,j,k) = i*1057 + j*33 + k
#define LDS_BYTES  (LDS_FLOATS * 4)     // 135,296 B (<160 KB/CU)

typedef float f4 __attribute__((ext_vector_type(4)));

// Output: out[b][s][c][l], s in 0..11.  flip = s+2
// q0->s0: l=i*1024+j*32+k   q1->s1: l=i*1024+k*32+j
// q2->s4: l=j*1024+k*32+i   q3->s5: l=j*1024+i*32+k
// q4->s8: l=k*1024+i*32+j   q5->s9: l=k*1024+j*32+i
// input addr = i*1024 + j*32 + k
//
// One block per (b,c) slice: read 128KB once, emit all 12 streams fully
// contiguous. LDS strides 1057 (i) and 33 (j) are both ==1 mod 32 -> every
// gather pattern is <=2-way bank aliasing (free on CDNA4).

__global__ __launch_bounds__(1024) void cross_scan3d(const float* __restrict__ in,
                                                     float* __restrict__ out) {
    extern __shared__ float lds[];

    const int bc  = blockIdx.x;        // b*96 + c
    const int b   = bc / NC;
    const int c   = bc % NC;
    const int tid = threadIdx.x;

    const f4* src4 = (const f4*)(in + (size_t)bc * L);
    #define OPTR(s) ((f4*)(out + ((size_t)((b)*12 + (s)) * NC + (c)) * L))
    #define NT(p, v) __builtin_nontemporal_store((v), (p))
    #define A(i, j, k) ((i) * 1057 + (j) * 33 + (k))

    f4* o0 = OPTR(0);  f4* o0f = OPTR(2);
    f4* o1 = OPTR(1);  f4* o1f = OPTR(3);
    f4* o2 = OPTR(4);  f4* o2f = OPTR(6);
    f4* o3 = OPTR(5);  f4* o3f = OPTR(7);
    f4* o4 = OPTR(8);  f4* o4f = OPTR(10);
    f4* o5 = OPTR(9);  f4* o5f = OPTR(11);

    // ---- load whole slice (contiguous, once); q0/q0f direct from registers ----
    #pragma unroll
    for (int it = 0; it < 8; ++it) {
        int t = it * 1024 + tid;               // t = i*256 + j*8 + k4
        f4 v = src4[t];
        int i = t >> 8, j = (t >> 3) & 31, k4 = t & 7;
        float* d = &lds[A(i, j, k4 * 4)];
        d[0] = v.x; d[1] = v.y; d[2] = v.z; d[3] = v.w;
        NT(o0 + t, v);
        f4 vr = { v.w, v.z, v.y, v.x };
        NT(o0f + (8191 - t), vr);
    }
    __syncthreads();

    // ---- q1: t = i*256 + k*8 + j4 ; elem e = x[i, j4*4+e, k] ----
    #pragma unroll
    for (int it = 0; it < 8; ++it) {
        int t = it * 1024 + tid;
        int i = t >> 8, k = (t >> 3) & 31, j4 = t & 7;
        f4 v;
        v.x = lds[A(i, j4 * 4 + 0, k)];
        v.y = lds[A(i, j4 * 4 + 1, k)];
        v.z = lds[A(i, j4 * 4 + 2, k)];
        v.w = lds[A(i, j4 * 4 + 3, k)];
        NT(o1 + t, v);
        f4 vr = { v.w, v.z, v.y, v.x };
        NT(o1f + (8191 - t), vr);
    }

    // ---- q3: t = j*256 + i*8 + k4 ; elem e = x[i, j, k4*4+e] ----
    #pragma unroll
    for (int it = 0; it < 8; ++it) {
        int t = it * 1024 + tid;
        int j = t >> 8, i = (t >> 3) & 31, k4 = t & 7;
        f4 v;
        v.x = lds[A(i, j, k4 * 4 + 0)];
        v.y = lds[A(i, j, k4 * 4 + 1)];
        v.z = lds[A(i, j, k4 * 4 + 2)];
        v.w = lds[A(i, j, k4 * 4 + 3)];
        NT(o3 + t, v);
        f4 vr = { v.w, v.z, v.y, v.x };
        NT(o3f + (8191 - t), vr);
    }

    // ---- q2: t = j*256 + k*8 + i4 ; elem e = x[i4*4+e, j, k] ----
    #pragma unroll
    for (int it = 0; it < 8; ++it) {
        int t = it * 1024 + tid;
        int j = t >> 8, k = (t >> 3) & 31, i4 = t & 7;
        f4 v;
        v.x = lds[A(i4 * 4 + 0, j, k)];
        v.y = lds[A(i4 * 4 + 1, j, k)];
        v.z = lds[A(i4 * 4 + 2, j, k)];
        v.w = lds[A(i4 * 4 + 3, j, k)];
        NT(o2 + t, v);
        f4 vr = { v.w, v.z, v.y, v.x };
        NT(o2f + (8191 - t), vr);
    }

    // ---- q4: t = k*256 + i*8 + j4 ; elem e = x[i, j4*4+e, k] ----
    #pragma unroll
    for (int it = 0; it < 8; ++it) {
        int t = it * 1024 + tid;
        int k = t >> 8, i = (t >> 3) & 31, j4 = t & 7;
        f4 v;
        v.x = lds[A(i, j4 * 4 + 0, k)];
        v.y = lds[A(i, j4 * 4 + 1, k)];
        v.z = lds[A(i, j4 * 4 + 2, k)];
        v.w = lds[A(i, j4 * 4 + 3, k)];
        NT(o4 + t, v);
        f4 vr = { v.w, v.z, v.y, v.x };
        NT(o4f + (8191 - t), vr);
    }

    // ---- q5: t = k*256 + j*8 + i4 ; elem e = x[i4*4+e, j, k] ----
    #pragma unroll
    for (int it = 0; it < 8; ++it) {
        int t = it * 1024 + tid;
        int k = t >> 8, j = (t >> 3) & 31, i4 = t & 7;
        f4 v;
        v.x = lds[A(i4 * 4 + 0, j, k)];
        v.y = lds[A(i4 * 4 + 1, j, k)];
        v.z = lds[A(i4 * 4 + 2, j, k)];
        v.w = lds[A(i4 * 4 + 3, j, k)];
        NT(o5 + t, v);
        f4 vr = { v.w, v.z, v.y, v.x };
        NT(o5f + (8191 - t), vr);
    }

    #undef OPTR
    #undef NT
    #undef A
}

extern "C" void kernel_launch(void* const* d_in, const int* in_sizes, int n_in,
                              void* d_out, int out_size, void* d_ws, size_t ws_size,
                              hipStream_t stream) {
    const float* in = (const float*)d_in[0];
    float* out = (float*)d_out;
    const int bc_count = in_sizes[0] / L;   // B*C = 192

    // allow >64KB dynamic LDS (host-side attribute, graph-capture safe)
    (void)hipFuncSetAttribute((const void*)cross_scan3d,
                              hipFuncAttributeMaxDynamicSharedMemorySize, LDS_BYTES);

    cross_scan3d<<<dim3(bc_count), 1024, LDS_BYTES, stream>>>(in, out);
}

// Round 7
// 60.330 us; speedup vs baseline: 1.3238x; 1.0232x over previous
//
#include <hip/hip_runtime.h>

#define L 32768           // 32*32*32
#define NC 96
#define LDS_FLOATS (32 * 1057)          // A(i,j,k) = i*1057 + j*33 + k
#define LDS_BYTES  (LDS_FLOATS * 4)     // 135,296 B (<160 KB/CU)

typedef float f4 __attribute__((ext_vector_type(4)));

// Output: out[b][s][c][l], s in 0..11.  flip = s+2
// q0->s0: l=i*1024+j*32+k   q1->s1: l=i*1024+k*32+j
// q2->s4: l=j*1024+k*32+i   q3->s5: l=j*1024+i*32+k
// q4->s8: l=k*1024+i*32+j   q5->s9: l=k*1024+j*32+i
// input addr = i*1024 + j*32 + k
//
// One block per (b,c) slice, read once. EVERY store stream ascending:
// flip scans gather reversed data (u = 8191-t, reverse4) instead of writing
// descending. One stream per phase, barrier-separated -> 192 concurrent
// ascending streams device-wide.

__global__ __launch_bounds__(1024) void cross_scan3d(const float* __restrict__ in,
                                                     float* __restrict__ out) {
    extern __shared__ float lds[];

    const int bc  = blockIdx.x;        // b*96 + c
    const int b   = bc / NC;
    const int c   = bc % NC;
    const int tid = threadIdx.x;

    const f4* src4 = (const f4*)(in + (size_t)bc * L);
    #define OPTR(s) ((f4*)(out + ((size_t)((b)*12 + (s)) * NC + (c)) * L))
    #define NT(p, v) __builtin_nontemporal_store((v), (p))
    #define A(i, j, k) ((i) * 1057 + (j) * 33 + (k))

    // gathers: u = source f4 index in scan-q ordering
    #define G0(v, u) { int i=(u)>>8, j=((u)>>3)&31, kb=((u)&7)*4;               \
        v.x=lds[A(i,j,kb+0)]; v.y=lds[A(i,j,kb+1)];                             \
        v.z=lds[A(i,j,kb+2)]; v.w=lds[A(i,j,kb+3)]; }
    #define G1(v, u) { int i=(u)>>8, k=((u)>>3)&31, jb=((u)&7)*4;               \
        v.x=lds[A(i,jb+0,k)]; v.y=lds[A(i,jb+1,k)];                             \
        v.z=lds[A(i,jb+2,k)]; v.w=lds[A(i,jb+3,k)]; }
    #define G2(v, u) { int j=(u)>>8, k=((u)>>3)&31, ib=((u)&7)*4;               \
        v.x=lds[A(ib+0,j,k)]; v.y=lds[A(ib+1,j,k)];                             \
        v.z=lds[A(ib+2,j,k)]; v.w=lds[A(ib+3,j,k)]; }
    #define G3(v, u) { int j=(u)>>8, i=((u)>>3)&31, kb=((u)&7)*4;               \
        v.x=lds[A(i,j,kb+0)]; v.y=lds[A(i,j,kb+1)];                             \
        v.z=lds[A(i,j,kb+2)]; v.w=lds[A(i,j,kb+3)]; }
    #define G4(v, u) { int k=(u)>>8, i=((u)>>3)&31, jb=((u)&7)*4;               \
        v.x=lds[A(i,jb+0,k)]; v.y=lds[A(i,jb+1,k)];                             \
        v.z=lds[A(i,jb+2,k)]; v.w=lds[A(i,jb+3,k)]; }
    #define G5(v, u) { int k=(u)>>8, j=((u)>>3)&31, ib=((u)&7)*4;               \
        v.x=lds[A(ib+0,j,k)]; v.y=lds[A(ib+1,j,k)];                             \
        v.z=lds[A(ib+2,j,k)]; v.w=lds[A(ib+3,j,k)]; }

    // base phase: ascending gather + ascending store
    #define PHASE_BASE(Gm, optr)                                                \
        _Pragma("unroll")                                                       \
        for (int it = 0; it < 8; ++it) {                                        \
            int t = it * 1024 + tid;                                            \
            f4 v; Gm(v, t);                                                     \
            NT((optr) + t, v);                                                  \
        }                                                                       \
        __syncthreads();

    // flip phase: ascending store of reversed gather
    #define PHASE_FLIP(Gm, optr)                                                \
        _Pragma("unroll")                                                       \
        for (int it = 0; it < 8; ++it) {                                        \
            int t = it * 1024 + tid;                                            \
            int u = 8191 - t;                                                   \
            f4 v; Gm(v, u);                                                     \
            f4 r = { v.w, v.z, v.y, v.x };                                      \
            NT((optr) + t, r);                                                  \
        }                                                                       \
        __syncthreads();

    // ---- load whole slice once; q0 emitted straight from registers ----
    {
        f4* o0 = OPTR(0);
        #pragma unroll
        for (int it = 0; it < 8; ++it) {
            int t = it * 1024 + tid;               // t = i*256 + j*8 + k4
            f4 v = __builtin_nontemporal_load(src4 + t);
            int i = t >> 8, j = (t >> 3) & 31, kb = (t & 7) * 4;
            float* d = &lds[A(i, j, kb)];
            d[0] = v.x; d[1] = v.y; d[2] = v.z; d[3] = v.w;
            NT(o0 + t, v);
        }
        __syncthreads();
    }

    PHASE_FLIP(G0, OPTR(2))     // q0f
    PHASE_BASE(G1, OPTR(1))     // q1
    PHASE_FLIP(G1, OPTR(3))     // q1f
    PHASE_BASE(G3, OPTR(5))     // q3
    PHASE_FLIP(G3, OPTR(7))     // q3f
    PHASE_BASE(G2, OPTR(4))     // q2
    PHASE_FLIP(G2, OPTR(6))     // q2f
    PHASE_BASE(G4, OPTR(8))     // q4
    PHASE_FLIP(G4, OPTR(10))    // q4f
    PHASE_BASE(G5, OPTR(9))     // q5
    PHASE_FLIP(G5, OPTR(11))    // q5f

    #undef OPTR
    #undef NT
    #undef A
}

extern "C" void kernel_launch(void* const* d_in, const int* in_sizes, int n_in,
                              void* d_out, int out_size, void* d_ws, size_t ws_size,
                              hipStream_t stream) {
    const float* in = (const float*)d_in[0];
    float* out = (float*)d_out;
    const int bc_count = in_sizes[0] / L;   // B*C = 192

    // allow >64KB dynamic LDS (host-side attribute, graph-capture safe)
    (void)hipFuncSetAttribute((const void*)cross_scan3d,
                              hipFuncAttributeMaxDynamicSharedMemorySize, LDS_BYTES);

    cross_scan3d<<<dim3(bc_count), 1024, LDS_BYTES, stream>>>(in, out);
}